// Round 1
// 863.071 us; speedup vs baseline: 1.0219x; 1.0219x over previous
//
#include <hip/hip_runtime.h>
#include <float.h>

#define D 128
#define CAP 512  // per-wave LDS score stash (counts ~Poisson(20); overflow -> global)

// ---------------------------------------------------------------------------
// Fused K1+K2: blocks [0, nProj) compute keys_proj (tiled fp32 GEMM);
// blocks [nProj, nProj+1024) do the index histogram. The two are independent,
// so fusing them into one launch lets them overlap on the machine.
// Branch is block-uniform -> __syncthreads in the proj path is safe.
// ---------------------------------------------------------------------------
__global__ __launch_bounds__(256) void k_proj_count(
    const float* __restrict__ attn_keys, const float* __restrict__ W,
    const float* __restrict__ bias, float* __restrict__ keys_proj, int M,
    const int* __restrict__ indices, int* __restrict__ counts, int N,
    int nProj) {
  __shared__ float sKey[32][D + 1];
  __shared__ float sWt[32][D + 1];
  const int tid = threadIdx.x;

  if (blockIdx.x >= nProj) {
    // ---- count path ----
    const int i = (blockIdx.x - nProj) * 256 + tid;
    const int stride = 1024 * 256;
    const int n4 = N >> 2;
    const int4* idx4 = (const int4*)indices;
    for (int j = i; j < n4; j += stride) {
      int4 v = idx4[j];
      atomicAdd(counts + v.x, 1);
      atomicAdd(counts + v.y, 1);
      atomicAdd(counts + v.z, 1);
      atomicAdd(counts + v.w, 1);
    }
    for (int j = (n4 << 2) + i; j < N; j += stride)
      atomicAdd(counts + indices[j], 1);
    return;
  }

  // ---- proj path: keys_proj[m][j] = sum_k attn_keys[m][k]*W[j][k] + b[j] ----
  const int tc = tid & 31;
  const int tr = tid >> 5;
  const int row0 = blockIdx.x * 32;

  for (int e = tid; e < 32 * D; e += 256) {
    int r = e >> 7, k = e & (D - 1);
    int row = row0 + r;
    sKey[r][k] = (row < M) ? attn_keys[(size_t)row * D + k] : 0.0f;
  }

  float acc[4][4];
#pragma unroll
  for (int i = 0; i < 4; ++i)
#pragma unroll
    for (int c = 0; c < 4; ++c) acc[i][c] = 0.0f;

  for (int kc = 0; kc < D; kc += 32) {
    __syncthreads();
    for (int e = tid; e < 32 * D; e += 256) {
      int k = e & 31, j = e >> 5;
      sWt[k][j] = W[(size_t)j * D + kc + k];
    }
    __syncthreads();
#pragma unroll 8
    for (int kk = 0; kk < 32; ++kk) {
      float kv[4], wv[4];
#pragma unroll
      for (int i = 0; i < 4; ++i) kv[i] = sKey[4 * tr + i][kc + kk];
#pragma unroll
      for (int c = 0; c < 4; ++c) wv[c] = sWt[kk][4 * tc + c];
#pragma unroll
      for (int i = 0; i < 4; ++i)
#pragma unroll
        for (int c = 0; c < 4; ++c) acc[i][c] += kv[i] * wv[c];
    }
  }

#pragma unroll
  for (int i = 0; i < 4; ++i) {
    int row = row0 + 4 * tr + i;
    if (row < M) {
#pragma unroll
      for (int c = 0; c < 4; ++c) {
        int j = 4 * tc + c;
        keys_proj[(size_t)row * D + j] = acc[i][c] + bias[j];
      }
    }
  }
}

// ---------------------------------------------------------------------------
// CSR build: offsets + fill (count is fused above)
// ---------------------------------------------------------------------------
__global__ __launch_bounds__(256) void k_offsets(
    const int* __restrict__ counts, int* __restrict__ fillpos,
    int* __restrict__ cursor, int M) {
  int m = blockIdx.x * blockDim.x + threadIdx.x;
  if (m < M) fillpos[m] = atomicAdd(cursor, counts[m]);
}

__global__ __launch_bounds__(256) void k_fill(
    const int* __restrict__ indices, int* __restrict__ fillpos,
    int* __restrict__ rowids, int N) {
  int i = blockIdx.x * blockDim.x + threadIdx.x;
  const int stride = gridDim.x * blockDim.x;
  const int n4 = N >> 2;
  const int4* idx4 = (const int4*)indices;
  for (int j = i; j < n4; j += stride) {
    int4 v = idx4[j];
    int base = 4 * j;
    rowids[atomicAdd(fillpos + v.x, 1)] = base;
    rowids[atomicAdd(fillpos + v.y, 1)] = base + 1;
    rowids[atomicAdd(fillpos + v.z, 1)] = base + 2;
    rowids[atomicAdd(fillpos + v.w, 1)] = base + 3;
  }
  for (int j = (n4 << 2) + i; j < N; j += stride)
    rowids[atomicAdd(fillpos + indices[j], 1)] = j;
}

// ---------------------------------------------------------------------------
// K5: one wave per segment. lane = 16*g + t; row-slot g in [0,4), col chunk t
// in [0,16). Lane t covers elements [4t,4t+4) and [64+4t,64+4t+4) so each
// 16-lane load instruction is a contiguous 256 B. Each group keeps a PRIVATE
// online-softmax state (run_m, run_l, acc) for its row-slot — no broadcast
// shuffles, 2 expf per row instead of a 4-deep uniform STEP chain — and the
// four states merge once at the end (xor-16/32 online-softmax merge).
// After k_fill, fillpos[m] == end of segment m.
// ---------------------------------------------------------------------------
__global__ __launch_bounds__(256) void k_segment(
    const float* __restrict__ values, const int* __restrict__ rowids,
    const int* __restrict__ counts, const int* __restrict__ fillpos,
    const float* __restrict__ keys_proj, float* __restrict__ raw_ovf,
    float* __restrict__ scores, float* __restrict__ attn_out, int M) {
  __shared__ float sS[4][CAP];
  const int lane = threadIdx.x & 63;
  const int wv = threadIdx.x >> 6;
  const int m = blockIdx.x * 4 + wv;
  if (m >= M) return;
  const int g = lane >> 4;  // row slot
  const int t = lane & 15;  // col chunk

  const int cnt = counts[m];
  const int start = fillpos[m] - cnt;

  const float4* kp = (const float4*)(keys_proj + (size_t)m * D);
  const float4 k1 = kp[t];
  const float4 k2 = kp[t + 16];
  const float4* vr = (const float4*)values;

  float run_m = -FLT_MAX, run_l = 0.0f;
  float4 accA = {0, 0, 0, 0}, accB = {0, 0, 0, 0};

  float4 a = {0, 0, 0, 0}, bb = {0, 0, 0, 0};
  if (cnt > 0) {
    int id = rowids[start + min(g, cnt - 1)];
    a = vr[(size_t)id * 32 + t];
    bb = vr[(size_t)id * 32 + 16 + t];
  }

  for (int gb = 0; gb < cnt; gb += 4) {
    const float4 ca = a, cb = bb;
    if (gb + 4 < cnt) {  // prefetch next group
      int nid = rowids[start + min(gb + 4 + g, cnt - 1)];
      a = vr[(size_t)nid * 32 + t];
      bb = vr[(size_t)nid * 32 + 16 + t];
    }
    float s = ca.x * k1.x + ca.y * k1.y + ca.z * k1.z + ca.w * k1.w +
              cb.x * k2.x + cb.y * k2.y + cb.z * k2.z + cb.w * k2.w;
    s += __shfl_xor(s, 1, 64);
    s += __shfl_xor(s, 2, 64);
    s += __shfl_xor(s, 4, 64);
    s += __shfl_xor(s, 8, 64);
    // group-private online softmax update (branch-free when inactive:
    // mn=run_m -> al=1, p=0 -> state unchanged)
    const bool act = (gb + g) < cnt;
    const float mn = act ? fmaxf(run_m, s) : run_m;
    const float al = __expf(run_m - mn);
    const float p = act ? __expf(s - mn) : 0.0f;
    run_l = run_l * al + p;
    run_m = mn;
    accA.x = accA.x * al + ca.x * p;
    accA.y = accA.y * al + ca.y * p;
    accA.z = accA.z * al + ca.z * p;
    accA.w = accA.w * al + ca.w * p;
    accB.x = accB.x * al + cb.x * p;
    accB.y = accB.y * al + cb.y * p;
    accB.z = accB.z * al + cb.z * p;
    accB.w = accB.w * al + cb.w * p;
    if (t == 0 && act) {  // 4 parallel stash writes (one per group)
      int r = gb + g;
      if (r < CAP) sS[wv][r] = s; else raw_ovf[start + r] = s;
    }
  }

  // merge the 4 group states: online-softmax combine across xor 16, 32
#pragma unroll
  for (int off = 16; off < 64; off <<= 1) {
    float om = __shfl_xor(run_m, off, 64);
    float ol = __shfl_xor(run_l, off, 64);
    float ax = __shfl_xor(accA.x, off, 64);
    float ay = __shfl_xor(accA.y, off, 64);
    float az = __shfl_xor(accA.z, off, 64);
    float aw = __shfl_xor(accA.w, off, 64);
    float bx = __shfl_xor(accB.x, off, 64);
    float by = __shfl_xor(accB.y, off, 64);
    float bz = __shfl_xor(accB.z, off, 64);
    float bw = __shfl_xor(accB.w, off, 64);
    const float mn = fmaxf(run_m, om);
    const float ea = __expf(run_m - mn);
    const float eb = __expf(om - mn);
    run_l = run_l * ea + ol * eb;
    accA.x = accA.x * ea + ax * eb;
    accA.y = accA.y * ea + ay * eb;
    accA.z = accA.z * ea + az * eb;
    accA.w = accA.w * ea + aw * eb;
    accB.x = accB.x * ea + bx * eb;
    accB.y = accB.y * ea + by * eb;
    accB.z = accB.z * ea + bz * eb;
    accB.w = accB.w * ea + bw * eb;
    run_m = mn;
  }

  const float invl = (run_l > 0.0f) ? 1.0f / run_l : 0.0f;
  if (g == 0) {
    float4* op = (float4*)(attn_out + (size_t)m * D);
    float4 oA = {accA.x * invl, accA.y * invl, accA.z * invl, accA.w * invl};
    float4 oB = {accB.x * invl, accB.y * invl, accB.z * invl, accB.w * invl};
    op[t] = oA;
    op[t + 16] = oB;
  }

  // finalize scores: lane-parallel over the segment's rows
  for (int r = lane; r < cnt; r += 64) {
    const float s = (r < CAP) ? sS[wv][r] : raw_ovf[start + r];
    const int i = rowids[start + r];
    scores[i] = __expf(s - run_m) * invl;
  }
}

extern "C" void kernel_launch(void* const* d_in, const int* in_sizes, int n_in,
                              void* d_out, int out_size, void* d_ws, size_t ws_size,
                              hipStream_t stream) {
  const float* values = (const float*)d_in[0];
  const int* indices = (const int*)d_in[1];
  const float* attn_keys = (const float*)d_in[2];
  const float* W = (const float*)d_in[3];
  const float* b = (const float*)d_in[4];
  const int N = in_sizes[0] / D;  // 1,000,000
  const int M = in_sizes[2] / D;  // 50,000

  // ws: keys_proj [M*D] | counts [M] | fillpos [M] | cursor [64] | rowids [N] | raw_ovf [N]
  float* keys_proj = (float*)d_ws;
  int* counts = (int*)(keys_proj + (size_t)M * D);
  int* fillpos = counts + M;
  int* cursor = fillpos + M;
  int* rowids = cursor + 64;
  float* raw_ovf = (float*)(rowids + N);

  float* scores = (float*)d_out;
  float* attn_out = scores + N;

  hipMemsetAsync(counts, 0, (size_t)M * sizeof(int), stream);
  hipMemsetAsync(cursor, 0, 64 * sizeof(int), stream);

  const int nProj = (M + 31) / 32;
  k_proj_count<<<nProj + 1024, 256, 0, stream>>>(attn_keys, W, b, keys_proj, M,
                                                 indices, counts, N, nProj);
  k_offsets<<<(M + 255) / 256, 256, 0, stream>>>(counts, fillpos, cursor, M);
  k_fill<<<1024, 256, 0, stream>>>(indices, fillpos, rowids, N);
  k_segment<<<(M + 3) / 4, 256, 0, stream>>>(values, rowids, counts, fillpos,
                                             keys_proj, raw_ovf, scores, attn_out, M);
}